// Round 1
// baseline (368.620 us; speedup 1.0000x reference)
//
#include <hip/hip_runtime.h>

#define SEQ 4096
#define DM  2048
#define DH  128
#define HSPLIT 8

typedef __attribute__((ext_vector_type(8))) short bf16x8;
typedef __attribute__((ext_vector_type(4))) short short4v;
typedef __attribute__((ext_vector_type(4))) float f32x4;

__device__ inline short f2bf(float f) {
    union { float f; unsigned u; } x; x.f = f;
    unsigned r = x.u + 0x7fffu + ((x.u >> 16) & 1u);
    return (short)(r >> 16);
}

// ---------------- Projection: C = A @ W^T + b, A [4096,2048] f32, W [128,2048] f32
// grid (64, 3), block 256.  mat 0->Q, 1->K, 2->V(transposed output)
__global__ __launch_bounds__(256) void proj_kernel(
    const float* __restrict__ inq, const float* __restrict__ ink, const float* __restrict__ inv,
    const float* __restrict__ wq, const float* __restrict__ bq,
    const float* __restrict__ wk, const float* __restrict__ bk,
    const float* __restrict__ wv, const float* __restrict__ bv,
    short* __restrict__ Qws, short* __restrict__ Kws, short* __restrict__ Vtws)
{
    const int mat = blockIdx.y;
    const float* A    = (mat == 0) ? inq : (mat == 1) ? ink : inv;
    const float* W    = (mat == 0) ? wq  : (mat == 1) ? wk  : wv;
    const float* bias = (mat == 0) ? bq  : (mat == 1) ? bk  : bv;

    __shared__ short Alds[64][72];    // 64 rows x 64 k (bf16), row padded to 72 (144B, 16B-mult)
    __shared__ short Wlds[128][72];

    const int tid  = threadIdx.x;
    const int lane = tid & 63;
    const int w    = tid >> 6;        // wave 0..3 -> rows 16w..16w+15 of tile
    const int i0   = blockIdx.x * 64;
    const int g    = lane >> 4;       // 0..3
    const int c16  = lane & 15;

    f32x4 acc[8];
    #pragma unroll
    for (int c = 0; c < 8; c++) acc[c] = (f32x4){0.f, 0.f, 0.f, 0.f};

    for (int kc = 0; kc < DM; kc += 64) {
        // stage A tile 64x64 (1024 float4, coalesced)
        #pragma unroll
        for (int j = 0; j < 4; j++) {
            int f = tid + 256 * j;
            int row = f >> 4, pos = f & 15;
            float4 v = *reinterpret_cast<const float4*>(A + (size_t)(i0 + row) * DM + kc + pos * 4);
            short4v s = { f2bf(v.x), f2bf(v.y), f2bf(v.z), f2bf(v.w) };
            *reinterpret_cast<short4v*>(&Alds[row][pos * 4]) = s;
        }
        // stage W tile 128x64 (2048 float4, coalesced)
        #pragma unroll
        for (int j = 0; j < 8; j++) {
            int f = tid + 256 * j;
            int row = f >> 4, pos = f & 15;
            float4 v = *reinterpret_cast<const float4*>(W + (size_t)row * DM + kc + pos * 4);
            short4v s = { f2bf(v.x), f2bf(v.y), f2bf(v.z), f2bf(v.w) };
            *reinterpret_cast<short4v*>(&Wlds[row][pos * 4]) = s;
        }
        __syncthreads();
        #pragma unroll
        for (int kk = 0; kk < 2; kk++) {
            bf16x8 afrag = *reinterpret_cast<const bf16x8*>(&Alds[w * 16 + c16][kk * 32 + g * 8]);
            #pragma unroll
            for (int c = 0; c < 8; c++) {
                bf16x8 bfrag = *reinterpret_cast<const bf16x8*>(&Wlds[c * 16 + c16][kk * 32 + g * 8]);
                acc[c] = __builtin_amdgcn_mfma_f32_16x16x32_bf16(afrag, bfrag, acc[c], 0, 0, 0);
            }
        }
        __syncthreads();
    }

    const int qrow0 = i0 + w * 16 + g * 4;   // + r
    if (mat < 2) {
        short* outp = (mat == 0) ? Qws : Kws;
        #pragma unroll
        for (int c = 0; c < 8; c++) {
            int col = c * 16 + c16;
            float bv_ = bias[col];
            #pragma unroll
            for (int r = 0; r < 4; r++)
                outp[(size_t)(qrow0 + r) * DH + col] = f2bf(acc[c][r] + bv_);
        }
    } else {
        #pragma unroll
        for (int c = 0; c < 8; c++) {
            int col = c * 16 + c16;
            float bv_ = bias[col];
            short4v s;
            #pragma unroll
            for (int r = 0; r < 4; r++) s[r] = f2bf(acc[c][r] + bv_);
            *reinterpret_cast<short4v*>(&Vtws[(size_t)col * SEQ + qrow0]) = s;
        }
    }
}

// ---------------- Flash attention with 8-way key split.
// grid (256, 8), block 64 (one wave). q-tile = 16 rows. j-tile = 64 keys.
__global__ __launch_bounds__(64) void flash_kernel(
    const short* __restrict__ Qws, const short* __restrict__ Kws, const short* __restrict__ Vtws,
    float* __restrict__ Opart, float* __restrict__ mpart, float* __restrict__ lpart)
{
    const int i  = blockIdx.x;     // q-tile 0..255
    const int h  = blockIdx.y;     // split 0..7
    const int i0 = i * 16;
    const int lane = threadIdx.x;
    const int g = lane >> 4, c16 = lane & 15;

    __shared__ short Slds[16][72]; // P round-trip: 16 q-rows x 64 keys (padded)

    bf16x8 qf[4];
    #pragma unroll
    for (int kk = 0; kk < 4; kk++)
        qf[kk] = *reinterpret_cast<const bf16x8*>(Qws + (size_t)(i0 + c16) * DH + kk * 32 + g * 8);

    float m[4], lsum[4];
    f32x4 O[8];
    #pragma unroll
    for (int r = 0; r < 4; r++) { m[r] = -__builtin_inff(); lsum[r] = 0.f; }
    #pragma unroll
    for (int c = 0; c < 8; c++) O[c] = (f32x4){0.f, 0.f, 0.f, 0.f};

    const int njt = i / 4 + 1;                 // 64-key tiles with j0 <= i0+15
    const float C = 0.03188448666f;            // log2(e)/sqrt(2048)

    for (int jt = h; jt < njt; jt += HSPLIT) {
        const int j0 = jt * 64;
        // S = Q K^T  (16 q-rows x 64 keys)
        f32x4 S[4];
        #pragma unroll
        for (int t = 0; t < 4; t++) S[t] = (f32x4){0.f, 0.f, 0.f, 0.f};
        #pragma unroll
        for (int kk = 0; kk < 4; kk++) {
            #pragma unroll
            for (int t = 0; t < 4; t++) {
                bf16x8 kf = *reinterpret_cast<const bf16x8*>(
                    Kws + (size_t)(j0 + t * 16 + c16) * DH + kk * 32 + g * 8);
                S[t] = __builtin_amdgcn_mfma_f32_16x16x32_bf16(qf[kk], kf, S[t], 0, 0, 0);
            }
        }
        // scale (+ causal mask; -inf/c == -inf so order matches reference)
        float s2[4][4];
        #pragma unroll
        for (int t = 0; t < 4; t++) {
            int key = j0 + t * 16 + c16;
            #pragma unroll
            for (int r = 0; r < 4; r++) {
                int q = i0 + g * 4 + r;
                s2[t][r] = (key > q) ? -__builtin_inff() : S[t][r] * C;
            }
        }
        // online softmax
        float mnew[4], alpha[4];
        #pragma unroll
        for (int r = 0; r < 4; r++) {
            float rm = fmaxf(fmaxf(s2[0][r], s2[1][r]), fmaxf(s2[2][r], s2[3][r]));
            rm = fmaxf(rm, __shfl_xor(rm, 1));
            rm = fmaxf(rm, __shfl_xor(rm, 2));
            rm = fmaxf(rm, __shfl_xor(rm, 4));
            rm = fmaxf(rm, __shfl_xor(rm, 8));
            mnew[r] = fmaxf(m[r], rm);
            alpha[r] = exp2f(m[r] - mnew[r]);   // m=-inf -> 0; rm always finite (j0<=q)
            m[r] = mnew[r];
        }
        #pragma unroll
        for (int r = 0; r < 4; r++) {
            float ps = 0.f;
            #pragma unroll
            for (int t = 0; t < 4; t++) {
                float p = exp2f(s2[t][r] - mnew[r]);
                ps += p;
                Slds[g * 4 + r][t * 16 + c16] = f2bf(p);
            }
            ps += __shfl_xor(ps, 1);
            ps += __shfl_xor(ps, 2);
            ps += __shfl_xor(ps, 4);
            ps += __shfl_xor(ps, 8);
            lsum[r] = lsum[r] * alpha[r] + ps;
            #pragma unroll
            for (int c = 0; c < 8; c++) O[c][r] *= alpha[r];
        }
        // O += P V   (P from LDS in A-layout, V^T frags from global)
        #pragma unroll
        for (int kk2 = 0; kk2 < 2; kk2++) {
            bf16x8 pf = *reinterpret_cast<const bf16x8*>(&Slds[c16][kk2 * 32 + g * 8]);
            #pragma unroll
            for (int c = 0; c < 8; c++) {
                bf16x8 vf = *reinterpret_cast<const bf16x8*>(
                    Vtws + (size_t)(c * 16 + c16) * SEQ + j0 + kk2 * 32 + g * 8);
                O[c] = __builtin_amdgcn_mfma_f32_16x16x32_bf16(pf, vf, O[c], 0, 0, 0);
            }
        }
    }
    // write partials (unnormalized O, running m, l)
    #pragma unroll
    for (int c = 0; c < 8; c++) {
        int col = c * 16 + c16;
        #pragma unroll
        for (int r = 0; r < 4; r++)
            Opart[((size_t)h * SEQ + i0 + g * 4 + r) * DH + col] = O[c][r];
    }
    if (c16 == 0) {
        #pragma unroll
        for (int r = 0; r < 4; r++) {
            mpart[h * SEQ + i0 + g * 4 + r] = m[r];
            lpart[h * SEQ + i0 + g * 4 + r] = lsum[r];
        }
    }
}

// ---------------- Merge the 8 split partials. grid 2048, block 256 (2 rows/block).
__global__ __launch_bounds__(256) void merge_kernel(
    const float* __restrict__ Opart, const float* __restrict__ mpart, const float* __restrict__ lpart,
    float* __restrict__ out)
{
    const int row = blockIdx.x * 2 + (threadIdx.x >> 7);
    const int col = threadIdx.x & 127;
    float mh[HSPLIT];
    float M = -__builtin_inff();
    #pragma unroll
    for (int hh = 0; hh < HSPLIT; hh++) {
        mh[hh] = mpart[hh * SEQ + row];
        M = fmaxf(M, mh[hh]);
    }
    float denom = 0.f, num = 0.f;
    #pragma unroll
    for (int hh = 0; hh < HSPLIT; hh++) {
        float wgt = exp2f(mh[hh] - M);          // -inf -> 0
        denom += lpart[hh * SEQ + row] * wgt;
        num   += Opart[((size_t)hh * SEQ + row) * DH + col] * wgt;
    }
    out[(size_t)row * DH + col] = num / denom;
}

extern "C" void kernel_launch(void* const* d_in, const int* in_sizes, int n_in,
                              void* d_out, int out_size, void* d_ws, size_t ws_size,
                              hipStream_t stream) {
    const float* inq = (const float*)d_in[0];
    const float* ink = (const float*)d_in[1];
    const float* inv = (const float*)d_in[2];
    const float* wq  = (const float*)d_in[3];
    const float* bq  = (const float*)d_in[4];
    const float* wk  = (const float*)d_in[5];
    const float* bk  = (const float*)d_in[6];
    const float* wv  = (const float*)d_in[7];
    const float* bv  = (const float*)d_in[8];

    char* ws = (char*)d_ws;
    short* Qws  = (short*)(ws);                          // 1 MB
    short* Kws  = (short*)(ws + (1u << 20));             // 1 MB
    short* Vtws = (short*)(ws + (2u << 20));             // 1 MB  (transposed [128][4096])
    float* Opart = (float*)(ws + (3u << 20));            // 8*4096*128*4 = 16 MB
    float* mpart = (float*)(ws + (19u << 20));           // 8*4096*4 = 128 KB
    float* lpart = mpart + HSPLIT * SEQ;                 // 128 KB

    proj_kernel<<<dim3(64, 3), 256, 0, stream>>>(inq, ink, inv, wq, bq, wk, bk, wv, bv,
                                                 Qws, Kws, Vtws);
    flash_kernel<<<dim3(256, HSPLIT), 64, 0, stream>>>(Qws, Kws, Vtws, Opart, mpart, lpart);
    merge_kernel<<<2048, 256, 0, stream>>>(Opart, mpart, lpart, (float*)d_out);
}

// Round 2
// 236.963 us; speedup vs baseline: 1.5556x; 1.5556x over previous
//
#include <hip/hip_runtime.h>

#define SEQ 4096
#define DM  2048
#define DH  128

typedef __attribute__((ext_vector_type(8))) short bf16x8;
typedef __attribute__((ext_vector_type(4))) short short4v;
typedef __attribute__((ext_vector_type(4))) float f32x4;

__device__ inline short f2bf(float f) {
    union { float f; unsigned u; } x; x.f = f;
    unsigned r = x.u + 0x7fffu + ((x.u >> 16) & 1u);
    return (short)(r >> 16);
}

// ---------------- W fp32 -> bf16 pre-convert. grid 768, block 256. Wbf[3][128][2048]
__global__ __launch_bounds__(256) void convw_kernel(
    const float* __restrict__ wq, const float* __restrict__ wk, const float* __restrict__ wv,
    short* __restrict__ Wbf)
{
    int idx = blockIdx.x * 256 + threadIdx.x;     // 196608 threads, 4 elems each
    int mat = idx >> 16;                          // 65536 float4-groups per matrix
    int off = (idx & 65535) * 4;
    const float* W = (mat == 0) ? wq : (mat == 1) ? wk : wv;
    float4 v = *reinterpret_cast<const float4*>(W + off);
    short4v s = { f2bf(v.x), f2bf(v.y), f2bf(v.z), f2bf(v.w) };
    *reinterpret_cast<short4v*>(Wbf + (size_t)mat * DH * DM + off) = s;
}

// ---------------- Projection: C = A @ W^T + b. grid (256, 3), block 256 (4 waves).
// Block: 16 rows x 128 cols. Wave w: cols [32w, 32w+32). A staged in dbuf LDS,
// W fragments straight from global (bf16, L1/L2-hot).
__global__ __launch_bounds__(256) void proj_kernel(
    const float* __restrict__ inq, const float* __restrict__ ink, const float* __restrict__ inv,
    const short* __restrict__ Wbf,
    const float* __restrict__ bq, const float* __restrict__ bk, const float* __restrict__ bv,
    short* __restrict__ Qws, short* __restrict__ Kws, short* __restrict__ Vtws)
{
    const int mat = blockIdx.y;
    const float* A    = (mat == 0) ? inq : (mat == 1) ? ink : inv;
    const short* W    = Wbf + (size_t)mat * DH * DM;
    const float* bias = (mat == 0) ? bq : (mat == 1) ? bk : bv;

    const int tid  = threadIdx.x;
    const int lane = tid & 63;
    const int w    = tid >> 6;
    const int g    = lane >> 4;
    const int c16  = lane & 15;
    const int i0   = blockIdx.x * 16;

    __shared__ short Alds[2][16][72];   // 16 rows x 64 k bf16, +8 pad

    const int arow = tid >> 4, apos = tid & 15;

    f32x4 acc0 = {0.f, 0.f, 0.f, 0.f}, acc1 = {0.f, 0.f, 0.f, 0.f};

    auto stage = [&](int b, int kc) {
        float4 v = *reinterpret_cast<const float4*>(A + (size_t)(i0 + arow) * DM + kc + apos * 4);
        short4v s = { f2bf(v.x), f2bf(v.y), f2bf(v.z), f2bf(v.w) };
        *reinterpret_cast<short4v*>(&Alds[b][arow][apos * 4]) = s;
    };
    auto compute = [&](int b, int kc) {
        #pragma unroll
        for (int kk = 0; kk < 2; kk++) {
            bf16x8 af = *reinterpret_cast<const bf16x8*>(&Alds[b][c16][kk * 32 + g * 8]);
            bf16x8 w0 = *reinterpret_cast<const bf16x8*>(
                W + (size_t)(w * 32 + c16) * DM + kc + kk * 32 + g * 8);
            bf16x8 w1 = *reinterpret_cast<const bf16x8*>(
                W + (size_t)(w * 32 + 16 + c16) * DM + kc + kk * 32 + g * 8);
            acc0 = __builtin_amdgcn_mfma_f32_16x16x32_bf16(af, w0, acc0, 0, 0, 0);
            acc1 = __builtin_amdgcn_mfma_f32_16x16x32_bf16(af, w1, acc1, 0, 0, 0);
        }
    };

    stage(0, 0);
    __syncthreads();
    for (int kc = 0; kc < DM; kc += 128) {
        stage(1, kc + 64);                    // kc+64 <= 1984 < 2048 always
        compute(0, kc);
        __syncthreads();
        if (kc + 128 < DM) stage(0, kc + 128);
        compute(1, kc + 64);
        __syncthreads();
    }

    const int col0 = w * 32 + c16, col1 = col0 + 16;
    const float b0 = bias[col0], b1 = bias[col1];
    if (mat < 2) {
        short* outp = (mat == 0) ? Qws : Kws;
        #pragma unroll
        for (int r = 0; r < 4; r++) {
            outp[(size_t)(i0 + g * 4 + r) * DH + col0] = f2bf(acc0[r] + b0);
            outp[(size_t)(i0 + g * 4 + r) * DH + col1] = f2bf(acc1[r] + b1);
        }
    } else {
        short4v s0, s1;
        #pragma unroll
        for (int r = 0; r < 4; r++) { s0[r] = f2bf(acc0[r] + b0); s1[r] = f2bf(acc1[r] + b1); }
        *reinterpret_cast<short4v*>(&Vtws[(size_t)col0 * SEQ + i0 + g * 4]) = s0;
        *reinterpret_cast<short4v*>(&Vtws[(size_t)col1 * SEQ + i0 + g * 4]) = s1;
    }
}

// ---------------- Flash attention, NS-way key split (NS = gridDim.y).
// grid (256, NS), block 64 (one wave). q-tile = 16 rows, j-tile = 64 keys.
__global__ __launch_bounds__(64) void flash_kernel(
    const short* __restrict__ Qws, const short* __restrict__ Kws, const short* __restrict__ Vtws,
    float* __restrict__ Opart, float* __restrict__ mpart, float* __restrict__ lpart)
{
    const int i  = blockIdx.x;
    const int h  = blockIdx.y;
    const int NS = gridDim.y;
    const int i0 = i * 16;
    const int lane = threadIdx.x;
    const int g = lane >> 4, c16 = lane & 15;

    __shared__ short Slds[16][72];

    bf16x8 qf[4];
    #pragma unroll
    for (int kk = 0; kk < 4; kk++)
        qf[kk] = *reinterpret_cast<const bf16x8*>(Qws + (size_t)(i0 + c16) * DH + kk * 32 + g * 8);

    float m[4], lsum[4];
    f32x4 O[8];
    #pragma unroll
    for (int r = 0; r < 4; r++) { m[r] = -__builtin_inff(); lsum[r] = 0.f; }
    #pragma unroll
    for (int c = 0; c < 8; c++) O[c] = (f32x4){0.f, 0.f, 0.f, 0.f};

    const int njt = i / 4 + 1;
    const float C = 0.03188448666f;            // log2(e)/sqrt(2048)

    for (int jt = h; jt < njt; jt += NS) {
        const int j0 = jt * 64;
        f32x4 S[4];
        #pragma unroll
        for (int t = 0; t < 4; t++) S[t] = (f32x4){0.f, 0.f, 0.f, 0.f};
        #pragma unroll
        for (int kk = 0; kk < 4; kk++) {
            #pragma unroll
            for (int t = 0; t < 4; t++) {
                bf16x8 kf = *reinterpret_cast<const bf16x8*>(
                    Kws + (size_t)(j0 + t * 16 + c16) * DH + kk * 32 + g * 8);
                S[t] = __builtin_amdgcn_mfma_f32_16x16x32_bf16(qf[kk], kf, S[t], 0, 0, 0);
            }
        }
        float s2[4][4];
        #pragma unroll
        for (int t = 0; t < 4; t++) {
            int key = j0 + t * 16 + c16;
            #pragma unroll
            for (int r = 0; r < 4; r++) {
                int q = i0 + g * 4 + r;
                s2[t][r] = (key > q) ? -__builtin_inff() : S[t][r] * C;
            }
        }
        float mnew[4], alpha[4];
        #pragma unroll
        for (int r = 0; r < 4; r++) {
            float rm = fmaxf(fmaxf(s2[0][r], s2[1][r]), fmaxf(s2[2][r], s2[3][r]));
            rm = fmaxf(rm, __shfl_xor(rm, 1));
            rm = fmaxf(rm, __shfl_xor(rm, 2));
            rm = fmaxf(rm, __shfl_xor(rm, 4));
            rm = fmaxf(rm, __shfl_xor(rm, 8));
            mnew[r] = fmaxf(m[r], rm);
            alpha[r] = exp2f(m[r] - mnew[r]);
            m[r] = mnew[r];
        }
        #pragma unroll
        for (int r = 0; r < 4; r++) {
            float ps = 0.f;
            #pragma unroll
            for (int t = 0; t < 4; t++) {
                float p = exp2f(s2[t][r] - mnew[r]);
                ps += p;
                Slds[g * 4 + r][t * 16 + c16] = f2bf(p);
            }
            ps += __shfl_xor(ps, 1);
            ps += __shfl_xor(ps, 2);
            ps += __shfl_xor(ps, 4);
            ps += __shfl_xor(ps, 8);
            lsum[r] = lsum[r] * alpha[r] + ps;
            #pragma unroll
            for (int c = 0; c < 8; c++) O[c][r] *= alpha[r];
        }
        #pragma unroll
        for (int kk2 = 0; kk2 < 2; kk2++) {
            bf16x8 pf = *reinterpret_cast<const bf16x8*>(&Slds[c16][kk2 * 32 + g * 8]);
            #pragma unroll
            for (int c = 0; c < 8; c++) {
                bf16x8 vf = *reinterpret_cast<const bf16x8*>(
                    Vtws + (size_t)(c * 16 + c16) * SEQ + j0 + kk2 * 32 + g * 8);
                O[c] = __builtin_amdgcn_mfma_f32_16x16x32_bf16(pf, vf, O[c], 0, 0, 0);
            }
        }
    }
    #pragma unroll
    for (int c = 0; c < 8; c++) {
        int col = c * 16 + c16;
        #pragma unroll
        for (int r = 0; r < 4; r++)
            Opart[((size_t)h * SEQ + i0 + g * 4 + r) * DH + col] = O[c][r];
    }
    if (c16 == 0) {
        #pragma unroll
        for (int r = 0; r < 4; r++) {
            mpart[h * SEQ + i0 + g * 4 + r] = m[r];
            lpart[h * SEQ + i0 + g * 4 + r] = lsum[r];
        }
    }
}

// ---------------- Merge NS split partials. grid 2048, block 256 (2 rows/block).
__global__ __launch_bounds__(256) void merge_kernel(
    const float* __restrict__ Opart, const float* __restrict__ mpart, const float* __restrict__ lpart,
    float* __restrict__ out, int NS)
{
    const int row = blockIdx.x * 2 + (threadIdx.x >> 7);
    const int col = threadIdx.x & 127;
    float mh[16];
    float M = -__builtin_inff();
    for (int hh = 0; hh < NS; hh++) {
        mh[hh] = mpart[hh * SEQ + row];
        M = fmaxf(M, mh[hh]);
    }
    float denom = 0.f, num = 0.f;
    for (int hh = 0; hh < NS; hh++) {
        float wgt = exp2f(mh[hh] - M);
        denom += lpart[hh * SEQ + row] * wgt;
        num   += Opart[((size_t)hh * SEQ + row) * DH + col] * wgt;
    }
    out[(size_t)row * DH + col] = num / denom;
}

extern "C" void kernel_launch(void* const* d_in, const int* in_sizes, int n_in,
                              void* d_out, int out_size, void* d_ws, size_t ws_size,
                              hipStream_t stream) {
    const float* inq = (const float*)d_in[0];
    const float* ink = (const float*)d_in[1];
    const float* inv = (const float*)d_in[2];
    const float* wq  = (const float*)d_in[3];
    const float* bq  = (const float*)d_in[4];
    const float* wk  = (const float*)d_in[5];
    const float* bk  = (const float*)d_in[6];
    const float* wv  = (const float*)d_in[7];
    const float* bv  = (const float*)d_in[8];

    const int NS = (ws_size >= (size_t)36 * 1024 * 1024) ? 16 : 8;

    char* ws = (char*)d_ws;
    short* Qws   = (short*)(ws);                         // 1 MB
    short* Kws   = (short*)(ws + (1u << 20));            // 1 MB
    short* Vtws  = (short*)(ws + (2u << 20));            // 1 MB (transposed [128][4096])
    short* Wbf   = (short*)(ws + (3u << 20));            // 1.5 MB (bf16 W, proj-only)
    float* Opart = (float*)(ws + (3u << 20));            // aliases Wbf: Wbf dead before flash
    float* mpart = (float*)(ws + (3u << 20) + (size_t)NS * SEQ * DH * 4);
    float* lpart = mpart + (size_t)NS * SEQ;

    convw_kernel<<<768, 256, 0, stream>>>(wq, wk, wv, Wbf);
    proj_kernel<<<dim3(256, 3), 256, 0, stream>>>(inq, ink, inv, Wbf, bq, bk, bv,
                                                  Qws, Kws, Vtws);
    flash_kernel<<<dim3(256, NS), 64, 0, stream>>>(Qws, Kws, Vtws, Opart, mpart, lpart);
    merge_kernel<<<2048, 256, 0, stream>>>(Opart, mpart, lpart, (float*)d_out, NS);
}